// Round 11
// baseline (112.625 us; speedup 1.0000x reference)
//
#include <hip/hip_runtime.h>
#include <math.h>

#define H 256
#define HH 128
#define B_GRAPHS 512

typedef __attribute__((ext_vector_type(8))) short bfrag8;   // 8 bf16
typedef __attribute__((ext_vector_type(16))) float f32x16;

// ---------------- K0: pre-split W1 into 2 bf16 planes (truncate + residual),
// fragment-major: base = ((kks*2+g)*128 + col)*8 + e, k = kks*16 + g*8 + e ----------------
__global__ void k_prep_w1(const float* __restrict__ W1, ushort* __restrict__ W1b) {
  const int idx = blockIdx.x * 256 + threadIdx.x;  // 32768 = 256*128
  const int k = idx >> 7, c = idx & 127;
  const float v = W1[idx];  // W1 is [256][128] row-major
  const uint u = __builtin_bit_cast(uint, v);
  const float r = v - __builtin_bit_cast(float, u & 0xFFFF0000u);
  const int base = (((k >> 4) * 2 + ((k >> 3) & 1)) * 128 + c) * 8 + (k & 7);
  W1b[base] = (ushort)(u >> 16);
  W1b[32768 + base] = (ushort)(__builtin_bit_cast(uint, r) >> 16);
}

// ---------------- K1: segment bounds (batch is sorted) ----------------
__global__ void k_seg_bounds(const int* __restrict__ batch, int* __restrict__ seg_start,
                             int N, int B) {
  int b = blockIdx.x * blockDim.x + threadIdx.x;
  if (b > B) return;
  int lo = 0, hi = N;
  while (lo < hi) {
    int mid = (lo + hi) >> 1;
    if (batch[mid] < b) lo = mid + 1; else hi = mid;
  }
  seg_start[b] = lo;
}

// ---------------- K2: score MLP — wave-contiguous x streaming + LDS A-planes ----------
__global__ __launch_bounds__(256, 4) void k_score_mfma(
    const float* __restrict__ x, const ushort* __restrict__ W1b,
    const float* __restrict__ b1, const float* __restrict__ W2,
    const float* __restrict__ b2, float* __restrict__ s_out) {
  __shared__ ushort ash[2][32][260];  // 2 bf16 planes of the 32x256 x-tile; 33,280 B
  const int t = threadIdx.x;
  const int lane = t & 63;
  const int w = t >> 6;          // wave 0..3
  const int nl = lane & 31, g = lane >> 5;
  const int node0 = blockIdx.x * 32;

  // ---- stage: wave w streams rows w*8..w*8+7; each instruction = contiguous 1 KB ----
  {
    const float* base = x + (size_t)node0 * H + w * 2048 + lane * 4;
    float4 v[8];
#pragma unroll
    for (int i = 0; i < 8; ++i) v[i] = *(const float4*)(base + i * 256);
#pragma unroll
    for (int i = 0; i < 8; ++i) {
      const int r = w * 8 + i;
      const float vals[4] = {v[i].x, v[i].y, v[i].z, v[i].w};
      ushort m[4], rr[4];
#pragma unroll
      for (int e = 0; e < 4; ++e) {
        const uint u = __builtin_bit_cast(uint, vals[e]);
        m[e] = (ushort)(u >> 16);
        const float res = vals[e] - __builtin_bit_cast(float, u & 0xFFFF0000u);
        rr[e] = (ushort)(__builtin_bit_cast(uint, res) >> 16);
      }
      *(uint2*)&ash[0][r][lane * 4] =
          make_uint2((uint)m[0] | ((uint)m[1] << 16), (uint)m[2] | ((uint)m[3] << 16));
      *(uint2*)&ash[1][r][lane * 4] =
          make_uint2((uint)rr[0] | ((uint)rr[1] << 16), (uint)rr[2] | ((uint)rr[3] << 16));
    }
  }
  __syncthreads();

  // ---- compute: wave w owns output 32 nodes x hid[w*32..w*32+32), full K ----
  f32x16 acc[2];
  acc[0] = (f32x16)0.f;
  acc[1] = (f32x16)0.f;
  const ushort* bbase = W1b + (size_t)(w * 32 + nl) * 8 + (size_t)g * 1024;

#pragma unroll
  for (int kks = 0; kks < 16; ++kks) {
    const bfrag8 a0 = *(const bfrag8*)&ash[0][nl][kks * 16 + g * 8];
    const bfrag8 a1 = *(const bfrag8*)&ash[1][nl][kks * 16 + g * 8];
    const bfrag8 b0 = *(const bfrag8*)(bbase + kks * 2048);
    const bfrag8 b1f = *(const bfrag8*)(bbase + kks * 2048 + 32768);
    acc[0] = __builtin_amdgcn_mfma_f32_32x32x16_bf16(a0, b0, acc[0], 0, 0, 0);
    acc[1] = __builtin_amdgcn_mfma_f32_32x32x16_bf16(a0, b1f, acc[1], 0, 0, 0);
    acc[0] = __builtin_amdgcn_mfma_f32_32x32x16_bf16(a1, b0, acc[0], 0, 0, 0);
  }

  // ---- epilogue: combine 4 waves' hid-quadrants via LDS, layer-2, shfl-reduce ----
  __syncthreads();  // all waves done reading ash
  float* part = (float*)ash;  // [32][132] floats = 16,896 B
#pragma unroll
  for (int r = 0; r < 16; ++r) {
    const int row = (r & 3) + 8 * (r >> 2) + 4 * g;
    part[row * 132 + w * 32 + nl] = acc[0][r] + acc[1][r];
  }
  __syncthreads();
  {
    const int node = t >> 3, seg = t & 7;
    float v = 0.f;
#pragma unroll
    for (int e = 0; e < 16; ++e) {
      const int hcol = seg * 16 + e;
      const float hv = part[node * 132 + hcol] + b1[hcol];
      v = fmaf(fmaxf(hv, 0.f), W2[hcol], v);
    }
#pragma unroll
    for (int m = 1; m <= 4; m <<= 1) v += __shfl_xor(v, m);
    if ((t & 7) == 0) s_out[node0 + node] = v + b2[0];
  }
}

// ---------------- K3: fused softmax stats + top-k select + single-pass pools ----------------
__global__ __launch_bounds__(512) void k_pool_fused(const float* __restrict__ x,
                                                    const float* __restrict__ s,
                                                    const int* __restrict__ seg_start,
                                                    float* __restrict__ pooled) {
  const int b = blockIdx.x;
  const int t = threadIdx.x;
  const int start = seg_start[b];
  const int end = seg_start[b + 1];
  const int n = end - start;

  __shared__ float s_lds[1024];
  __shared__ float red[512];
  __shared__ float thr_sh;
  __shared__ int thri_sh;
  __shared__ float r4[8][264];

  const bool fits = (n <= 1024);
  if (fits) {
    for (int i = t; i < n; i += 512) s_lds[i] = s[start + i];
  }
  __syncthreads();
  const float* sseg = fits ? s_lds : (s + start);

  float m = -INFINITY;
  for (int i = t; i < n; i += 512) m = fmaxf(m, sseg[i]);
  red[t] = m;
  __syncthreads();
  for (int off = 256; off > 0; off >>= 1) {
    if (t < off) red[t] = fmaxf(red[t], red[t + off]);
    __syncthreads();
  }
  const float smax = red[0];
  __syncthreads();
  float d = 0.f;
  for (int i = t; i < n; i += 512) d += __expf(sseg[i] - smax);
  red[t] = d;
  __syncthreads();
  for (int off = 256; off > 0; off >>= 1) {
    if (t < off) red[t] += red[t + off];
    __syncthreads();
  }
  const float denom = red[0];
  __syncthreads();
  const float inv_denom = (denom > 0.f) ? 1.f / denom : 0.f;

  int k = 0;
  if (n > 0) {
    k = (int)ceilf(0.05f * (float)n);
    if (k < 5) k = 5;
    if (k > 64) k = 64;
    if (k > n) k = n;
  }

  if (t < 64) {
    float pk = INFINITY;
    int pidx = -1;
    for (int r = 0; r < k; ++r) {
      float bk = -INFINITY;
      int bi = 0x7fffffff;
      for (int i = t; i < n; i += 64) {
        const float si = sseg[i];
        const int gi = start + i;
        const bool below = (si < pk) || (si == pk && gi > pidx);
        if (below && (si > bk || (si == bk && gi < bi))) { bk = si; bi = gi; }
      }
#pragma unroll
      for (int off = 32; off > 0; off >>= 1) {
        const float ok = __shfl_xor(bk, off);
        const int oi = __shfl_xor(bi, off);
        if (ok > bk || (ok == bk && oi < bi)) { bk = ok; bi = oi; }
      }
      pk = bk;
      pidx = bi;
    }
    if (t == 0) {
      thr_sh = (k > 0) ? pk : INFINITY;
      thri_sh = (k > 0) ? pidx : -1;
    }
  }
  __syncthreads();
  const float thr = thr_sh;
  const int thri = thri_sh;

  const int fq = t & 63;
  const int sub = t >> 6;
  float mean[4] = {0.f, 0.f, 0.f, 0.f};
  float attn[4] = {0.f, 0.f, 0.f, 0.f};
  float tk[4] = {0.f, 0.f, 0.f, 0.f};
  float mx[4] = {-INFINITY, -INFINITY, -INFINITY, -INFINITY};
  for (int i = sub; i < n; i += 8) {
    const float si = sseg[i];
    const float wi = __expf(si - smax);
    const int gi = start + i;
    const bool sel = (si > thr) || (si == thr && gi <= thri);
    const float4 xv = *reinterpret_cast<const float4*>(x + (size_t)gi * H + fq * 4);
    mean[0] += xv.x; mean[1] += xv.y; mean[2] += xv.z; mean[3] += xv.w;
    attn[0] = fmaf(xv.x, wi, attn[0]);
    attn[1] = fmaf(xv.y, wi, attn[1]);
    attn[2] = fmaf(xv.z, wi, attn[2]);
    attn[3] = fmaf(xv.w, wi, attn[3]);
    mx[0] = fmaxf(mx[0], xv.x);
    mx[1] = fmaxf(mx[1], xv.y);
    mx[2] = fmaxf(mx[2], xv.z);
    mx[3] = fmaxf(mx[3], xv.w);
    if (sel) {
      tk[0] += xv.x; tk[1] += xv.y; tk[2] += xv.z; tk[3] += xv.w;
    }
  }
  float* po = pooled + (size_t)b * 1024;
  const float invn = 1.f / (float)(n > 0 ? n : 1);
  const float invk = (k > 0) ? 1.f / (float)k : 0.f;
  *reinterpret_cast<float4*>(&r4[sub][fq * 4]) = make_float4(mean[0], mean[1], mean[2], mean[3]);
  __syncthreads();
  if (t < 256) {
    float tot = 0.f;
#pragma unroll
    for (int q = 0; q < 8; ++q) tot += r4[q][t];
    po[t] = tot * invn;
  }
  __syncthreads();
  *reinterpret_cast<float4*>(&r4[sub][fq * 4]) = make_float4(attn[0], attn[1], attn[2], attn[3]);
  __syncthreads();
  if (t < 256) {
    float tot = 0.f;
#pragma unroll
    for (int q = 0; q < 8; ++q) tot += r4[q][t];
    po[256 + t] = tot * inv_denom;
  }
  __syncthreads();
  *reinterpret_cast<float4*>(&r4[sub][fq * 4]) = make_float4(mx[0], mx[1], mx[2], mx[3]);
  __syncthreads();
  if (t < 256) {
    float tot = -INFINITY;
#pragma unroll
    for (int q = 0; q < 8; ++q) tot = fmaxf(tot, r4[q][t]);
    po[512 + t] = (n > 0) ? tot : 0.f;
  }
  __syncthreads();
  *reinterpret_cast<float4*>(&r4[sub][fq * 4]) = make_float4(tk[0], tk[1], tk[2], tk[3]);
  __syncthreads();
  if (t < 256) {
    float tot = 0.f;
#pragma unroll
    for (int q = 0; q < 8; ++q) tot += r4[q][t];
    po[768 + t] = tot * invk;
  }
}

// ---------------- K5: final GEMM [512,1024]@[1024,256], split-K=8 ----------------
__global__ __launch_bounds__(256) void k_gemm(const float* __restrict__ pooled,
                                              const float* __restrict__ Wf,
                                              float* __restrict__ gacc) {
  const int t = threadIdx.x;
  const int r0 = blockIdx.x * 8;
  const int kc0 = blockIdx.y * 128;
  __shared__ float ps[8][132];
  {
    const int r = t >> 5;
    const int c = (t & 31) << 2;
    *reinterpret_cast<float4*>(&ps[r][c]) =
        *reinterpret_cast<const float4*>(pooled + (size_t)(r0 + r) * 1024 + kc0 + c);
  }
  __syncthreads();
  float acc[8];
#pragma unroll
  for (int r = 0; r < 8; ++r) acc[r] = 0.f;
#pragma unroll 4
  for (int c = 0; c < 128; ++c) {
    const float wf = Wf[(size_t)(kc0 + c) * 256 + t];
#pragma unroll
    for (int r = 0; r < 8; ++r) acc[r] = fmaf(ps[r][c], wf, acc[r]);
  }
  float* go = gacc + ((size_t)blockIdx.y * B_GRAPHS + r0) * 256;
#pragma unroll
  for (int r = 0; r < 8; ++r) go[r * 256 + t] = acc[r];
}

// ---------------- K6: reduce split-K + bias + relu -> out ----------------
__global__ __launch_bounds__(256) void k_out(const float* __restrict__ gacc,
                                             const float* __restrict__ bf,
                                             float* __restrict__ out) {
  const int i = blockIdx.x * 256 + threadIdx.x;
  float v = bf[i & 255];
#pragma unroll
  for (int ks = 0; ks < 8; ++ks) v += gacc[(size_t)ks * (B_GRAPHS * 256) + i];
  out[i] = fmaxf(v, 0.f);
}

extern "C" void kernel_launch(void* const* d_in, const int* in_sizes, int n_in,
                              void* d_out, int out_size, void* d_ws, size_t ws_size,
                              hipStream_t stream) {
  const float* x  = (const float*)d_in[0];
  const int* batch = (const int*)d_in[1];
  const float* W1 = (const float*)d_in[2];
  const float* b1 = (const float*)d_in[3];
  const float* W2 = (const float*)d_in[4];
  const float* b2 = (const float*)d_in[5];
  const float* Wf = (const float*)d_in[6];
  const float* bf = (const float*)d_in[7];
  const int N = in_sizes[1];     // 131072
  const int B = B_GRAPHS;

  // ws floats: s[N] | seg_start[1024 ints] | pooled[B*1024] | gacc[8*B*256] | W1b[2*32768 u16]
  float* ws = (float*)d_ws;
  float* s = ws;
  int* seg_start = (int*)(ws + N);
  float* pooled = ws + N + 1024;
  float* gacc = pooled + (size_t)B * 1024;
  ushort* W1b = (ushort*)(gacc + (size_t)8 * B * 256);

  k_prep_w1<<<dim3(128), dim3(256), 0, stream>>>(W1, W1b);
  k_seg_bounds<<<dim3((B + 1 + 255) / 256), dim3(256), 0, stream>>>(batch, seg_start, N, B);
  k_score_mfma<<<dim3(N / 32), dim3(256), 0, stream>>>(x, W1b, b1, W2, b2, s);
  k_pool_fused<<<dim3(B), dim3(512), 0, stream>>>(x, s, seg_start, pooled);
  k_gemm<<<dim3(B / 8, 8), dim3(256), 0, stream>>>(pooled, Wf, gacc);
  k_out<<<dim3((B * 256) / 256), dim3(256), 0, stream>>>(gacc, bf, (float*)d_out);
}